// Round 4
// baseline (371.405 us; speedup 1.0000x reference)
//
#include <hip/hip_runtime.h>
#include <cstdint>

#define NITEMS   100000
#define BROWS    512
#define DDIM     64
#define NC       128                // columns per chunk/block
#define NCHUNKS  782                // ceil(100000/128)

// ---------------- Threefry-2x32-20, key = (0, 42)  (jax.random.key(42)) ----
// Core verified against JAX test vector threefry_2x32((0,0),(0,0)) ==
// (0x6b200159, 0x99ba4efe).
// Scheme ladder:
//   R1: non-partitionable split-half (e, e+25.6M), x0/x1  -> FAIL
//   R2: partitionable (hi=0, lo=e), take x1               -> FAIL
//   R3: partitionable (hi=0, lo=e), take x0               -> FAIL
//   R4 (this): partitionable (hi=0, lo=e), take x0 ^ x1
//        -- matches jax/_src/prng.py _threefry_random_bits_partitionable:
//           bit_width in [8,16,32] -> return bits1 ^ bits2
__device__ __forceinline__ uint32_t threefry_0_42_xor(uint32_t e) {
    const uint32_t K1 = 42u;
    const uint32_t K2 = 0x1BD11BDAu ^ 42u;   // K0 = 0
    uint32_t x0 = 0u;           // counts_hi + K0 (=0)
    uint32_t x1 = e + K1;       // counts_lo + K1
#define TFR(r) { x0 += x1; x1 = (x1 << (r)) | (x1 >> (32 - (r))); x1 ^= x0; }
    TFR(13) TFR(15) TFR(26) TFR(6)
    x0 += K1;  x1 += K2 + 1u;
    TFR(17) TFR(29) TFR(16) TFR(24)
    x0 += K2;  x1 += 2u;               // + K0 + 2
    TFR(13) TFR(15) TFR(26) TFR(6)
    /* x0 += K0 (=0) */ x1 += K1 + 3u;
    TFR(17) TFR(29) TFR(16) TFR(24)
    x0 += K1;  x1 += K2 + 4u;
    TFR(13) TFR(15) TFR(26) TFR(6)
    x0 += K2;  x1 += 5u;               // + K0 + 5
#undef TFR
    return x0 ^ x1;                     // bits1 ^ bits2
}

// jax uniform(minval=tiny,maxval=1) -> gumbel = -log(-log(u))
__device__ __forceinline__ float gumbel_from_bits(uint32_t b) {
    float f = __uint_as_float((b >> 9) | 0x3F800000u) - 1.0f;   // [0,1)
    f = fmaxf(f, 1.17549435e-38f);                               // tiny clamp
    return -logf(-logf(f));                                      // precise logf
}

// orderable mapping for float -> uint32 (monotone)
__device__ __forceinline__ uint32_t order_map(float v) {
    uint32_t x = __float_as_uint(v);
    return (x & 0x80000000u) ? ~x : (x | 0x80000000u);
}

// ---------------- Kernel A: uif = UF @ W.T + b ; also init packed ----------
__global__ void uif_kernel(const float* __restrict__ UF,    // 512 x 128
                           const float* __restrict__ W,     // 64 x 128
                           const float* __restrict__ bias,  // 64
                           float* __restrict__ uif,         // 512 x 64
                           unsigned long long* __restrict__ packed) {
    int b = blockIdx.x;     // 512
    int d = threadIdx.x;    // 64
    if (d == 0) packed[b] = 0ull;
    const float* w = W + d * 128;
    const float* u = UF + b * 128;
    float s = 0.f;
    for (int k = 0; k < 128; k++) s = fmaf(u[k], w[k], s);
    uif[b * 64 + d] = s + bias[d];
}

// ---------------- Kernel B: score + gumbel, per-row argmax via atomicMax ---
__global__ __launch_bounds__(256, 2) void score_argmax_kernel(
        const float* __restrict__ A,     // NITEMS x 64
        const float* __restrict__ uif,   // 512 x 64
        unsigned long long* __restrict__ packed) {
    __shared__ float As[NC * DDIM];      // 32 KB
    const int tid = threadIdx.x;
    const int p   = tid;                 // thread owns rows p and p+256

    // load both uif rows into registers (128 VGPRs)
    float u0[DDIM], u1[DDIM];
    {
        const float4* uif4 = (const float4*)uif;
#pragma unroll
        for (int k = 0; k < 16; k++) {
            float4 a = uif4[p * 16 + k];
            u0[4*k] = a.x; u0[4*k+1] = a.y; u0[4*k+2] = a.z; u0[4*k+3] = a.w;
        }
#pragma unroll
        for (int k = 0; k < 16; k++) {
            float4 a = uif4[(p + 256) * 16 + k];
            u1[4*k] = a.x; u1[4*k+1] = a.y; u1[4*k+2] = a.z; u1[4*k+3] = a.w;
        }
    }

    const int nbase  = blockIdx.x * NC;
    const int nvalid = min(NC, NITEMS - nbase);

    // stage A chunk to LDS (coalesced float4)
    {
        const float4* Ag  = (const float4*)(A + (size_t)nbase * DDIM);
        float4*       As4 = (float4*)As;
        const int cnt = nvalid * (DDIM / 4);
        for (int i = tid; i < cnt; i += 256) As4[i] = Ag[i];
    }
    __syncthreads();

    float best0 = -3.0e38f, best1 = -3.0e38f;
    int   bi0 = 0, bi1 = 0;
    // flat element index e = row * NITEMS + n
    const uint32_t e0base = (uint32_t)p * (uint32_t)NITEMS + (uint32_t)nbase;
    const uint32_t e1base = (uint32_t)(p + 256) * (uint32_t)NITEMS + (uint32_t)nbase;

    for (int j = 0; j < nvalid; j++) {
        uint32_t r0 = threefry_0_42_xor(e0base + (uint32_t)j);
        uint32_t r1 = threefry_0_42_xor(e1base + (uint32_t)j);
        float g0 = gumbel_from_bits(r0);
        float g1 = gumbel_from_bits(r1);

        float s0 = 0.f, s1 = 0.f;
        const float4* a4 = (const float4*)(As + j * DDIM);   // wave-uniform -> broadcast
#pragma unroll
        for (int k = 0; k < 16; k++) {
            float4 av = a4[k];
            s0 = fmaf(av.x, u0[4*k  ], s0);
            s0 = fmaf(av.y, u0[4*k+1], s0);
            s0 = fmaf(av.z, u0[4*k+2], s0);
            s0 = fmaf(av.w, u0[4*k+3], s0);
            s1 = fmaf(av.x, u1[4*k  ], s1);
            s1 = fmaf(av.y, u1[4*k+1], s1);
            s1 = fmaf(av.z, u1[4*k+2], s1);
            s1 = fmaf(av.w, u1[4*k+3], s1);
        }
        float v0 = s0 + g0, v1 = s1 + g1;
        if (v0 > best0) { best0 = v0; bi0 = nbase + j; }
        if (v1 > best1) { best1 = v1; bi1 = nbase + j; }
    }

    // pack: high32 = orderable value, low32 = ~idx (ties -> lowest idx wins)
    unsigned long long pk0 =
        ((unsigned long long)order_map(best0) << 32) | (uint32_t)(~(uint32_t)bi0);
    unsigned long long pk1 =
        ((unsigned long long)order_map(best1) << 32) | (uint32_t)(~(uint32_t)bi1);
    atomicMax(&packed[p],       pk0);
    atomicMax(&packed[p + 256], pk1);
}

// ---------------- Kernel C: decode idx, gather feat, cosine sim ------------
__global__ void finalize_kernel(const unsigned long long* __restrict__ packed,
                                const float* __restrict__ A,
                                const int* __restrict__ need_replace,
                                float* __restrict__ out,
                                float* __restrict__ sims) {
    int b    = blockIdx.x;   // 512
    int lane = threadIdx.x;  // 64
    unsigned long long pk = packed[b];
    int idx = (int)(~(uint32_t)(pk & 0xFFFFFFFFull));

    float fr = A[(size_t)idx * DDIM + lane];
    out[512 + b * DDIM + lane] = fr;                 // replaceable_feat

    int   item = need_replace[2 * b + 1];
    float fa   = A[(size_t)item * DDIM + lane];

    float dot = fa * fr, na2 = fa * fa, nb2 = fr * fr;
#pragma unroll
    for (int o = 32; o >= 1; o >>= 1) {
        dot += __shfl_down(dot, o);
        na2 += __shfl_down(na2, o);
        nb2 += __shfl_down(nb2, o);
    }
    if (lane == 0) {
        out[b] = (float)idx;                         // replaceable_items
        float denom = fmaxf(sqrtf(na2) * sqrtf(nb2), 1e-6f);
        float sim = dot / denom;
        sims[b] = (sim + 1.0f) * 0.5f;
    }
}

// ---------------- Kernel D: loss scalars -----------------------------------
__global__ void loss_kernel(const float* __restrict__ sims,
                            float* __restrict__ out) {
    __shared__ float shL[8], shS[8];
    int t = threadIdx.x;                 // 512 threads
    float s = sims[t];
    float d = s - 0.5f;
    float l = d * d;
#pragma unroll
    for (int o = 32; o >= 1; o >>= 1) {
        l += __shfl_down(l, o);
        s += __shfl_down(s, o);
    }
    int w = t >> 6;
    if ((t & 63) == 0) { shL[w] = l; shS[w] = s; }
    __syncthreads();
    if (t == 0) {
        float L = 0.f, S = 0.f;
        for (int i = 0; i < 8; i++) { L += shL[i]; S += shS[i]; }
        out[512 + 512 * DDIM]     = L / 512.0f;      // similarity_loss
        out[512 + 512 * DDIM + 1] = S / 512.0f;      // mean(sim)
    }
}

extern "C" void kernel_launch(void* const* d_in, const int* in_sizes, int n_in,
                              void* d_out, int out_size, void* d_ws, size_t ws_size,
                              hipStream_t stream) {
    (void)in_sizes; (void)n_in; (void)out_size; (void)ws_size;
    const int*   need_replace = (const int*)d_in[0];
    const float* UF           = (const float*)d_in[1];
    const float* A            = (const float*)d_in[2];
    const float* W            = (const float*)d_in[3];
    const float* bias         = (const float*)d_in[4];
    float* out = (float*)d_out;

    char* ws = (char*)d_ws;
    float*              uif    = (float*)ws;                         // 131072 B
    unsigned long long* packed = (unsigned long long*)(ws + 131072); // 4096 B
    float*              sims   = (float*)(ws + 131072 + 4096);       // 2048 B

    uif_kernel<<<BROWS, DDIM, 0, stream>>>(UF, W, bias, uif, packed);
    score_argmax_kernel<<<NCHUNKS, 256, 0, stream>>>(A, uif, packed);
    finalize_kernel<<<BROWS, DDIM, 0, stream>>>(packed, A, need_replace, out, sims);
    loss_kernel<<<1, 512, 0, stream>>>(sims, out);
}